// Round 1
// baseline (919.585 us; speedup 1.0000x reference)
//
#include <hip/hip_runtime.h>
#include <math.h>

namespace {
constexpr int B_ = 4, H_ = 16, T_ = 2048, K_ = 128, V_ = 128;
constexpr int BHn = B_ * H_;
constexpr int CB  = 32;          // time steps staged per chunk
constexpr int NS  = 4;           // V-dim slices (one block each)
constexpr int VS  = V_ / NS;     // 32 columns per block
constexpr int NCH = T_ / CB;     // 64 chunks
constexpr float SCALE = 0.08838834764831845f; // 128^-0.5
}

__global__ __launch_bounds__(256, 1)
void gdn_scan_kernel(const float* __restrict__ qg, const float* __restrict__ kgl,
                     const float* __restrict__ vg, const float* __restrict__ gg,
                     const float* __restrict__ bg, const float* __restrict__ s0,
                     float* __restrict__ out)
{
  const int bh = blockIdx.x >> 2;        // head index 0..63
  const int v0 = (blockIdx.x & 3) * VS;  // V-slice base
  const int t  = threadIdx.x;
  const int vp = t & 31;                 // owned V column (within slice)
  const int kq = t >> 5;                 // k-group 0..7 (16 k's each)
  const int l  = t & 63;
  const int w  = t >> 6;                 // wave 0..3

  __shared__ __align__(16) float ls_q[CB][K_];
  __shared__ __align__(16) float ls_k[CB][K_];
  __shared__ __align__(16) float ls_v[CB][VS];
  __shared__ float ls_eg[CB], ls_bt[CB], ls_qn[CB], ls_kn[CB];
  __shared__ float ls_pk[2][4][32];                 // kS partials, dbuf by step parity
  __shared__ __align__(16) float ls_po[CB][4][32];  // o partials per step

  // state strip: S[kq*16+i][v0+vp]
  float S[16];
  {
    const float* sp = s0 + ((size_t)bh * K_ + kq * 16) * V_ + v0 + vp;
    #pragma unroll
    for (int i = 0; i < 16; ++i) S[i] = sp[(size_t)i * V_];
  }

  const float* qh = qg  + (size_t)bh * T_ * K_;
  const float* kh = kgl + (size_t)bh * T_ * K_;
  float* oh = out + (size_t)bh * T_ * V_;

  for (int ch = 0; ch < NCH; ++ch) {
    const int t0 = ch * CB;
    // ---- stage 32 steps of q,k,v,g,beta into LDS (coalesced float4) ----
    {
      const float4* q4 = (const float4*)(qh + (size_t)t0 * K_);
      const float4* k4 = (const float4*)(kh + (size_t)t0 * K_);
      float4* lq4 = (float4*)&ls_q[0][0];
      float4* lk4 = (float4*)&ls_k[0][0];
      #pragma unroll
      for (int r = 0; r < 4; ++r) {
        lq4[t + 256 * r] = q4[t + 256 * r];
        lk4[t + 256 * r] = k4[t + 256 * r];
      }
      {
        int c = t >> 3, x = t & 7;
        ((float4*)&ls_v[c][0])[x] =
            ((const float4*)(vg + ((size_t)bh * T_ + t0 + c) * V_ + v0))[x];
      }
      if (t < CB)          ls_eg[t]      = expf(gg[(size_t)bh * T_ + t0 + t]);
      else if (t < 2 * CB) ls_bt[t - CB] = bg[(size_t)bh * T_ + t0 + (t - CB)];
    }
    __syncthreads();
    // ---- per-row l2 norms of q,k (4 threads per row) ----
    {
      int row = t >> 2, sub = t & 3;
      const float4* src = (const float4*)((row < CB) ? &ls_q[row][0] : &ls_k[row - CB][0]);
      float s = 0.f;
      #pragma unroll
      for (int j = 0; j < 8; ++j) {
        float4 x = src[sub * 8 + j];
        s += x.x * x.x + x.y * x.y + x.z * x.z + x.w * x.w;
      }
      s += __shfl_xor(s, 1);
      s += __shfl_xor(s, 2);
      if (sub == 0) {
        float n = fmaxf(sqrtf(s), 1e-12f);
        if (row < CB) ls_qn[row]      = SCALE / n;  // fold q-scale into norm
        else          ls_kn[row - CB] = 1.f / n;
      }
    }
    __syncthreads();
    // ---- 32 sequential recurrence steps ----
    #pragma unroll 2
    for (int c = 0; c < CB; ++c) {
      const int pb = c & 1;
      const float eg = ls_eg[c];
      const float kn = ls_kn[c];
      float4 kv[4];
      #pragma unroll
      for (int i = 0; i < 4; ++i) kv[i] = *(const float4*)&ls_k[c][kq * 16 + 4 * i];
      // decay + kS partial
      float p = 0.f;
      #pragma unroll
      for (int i = 0; i < 4; ++i) {
        S[4*i+0] *= eg; p += kv[i].x * S[4*i+0];
        S[4*i+1] *= eg; p += kv[i].y * S[4*i+1];
        S[4*i+2] *= eg; p += kv[i].z * S[4*i+2];
        S[4*i+3] *= eg; p += kv[i].w * S[4*i+3];
      }
      p *= kn;                       // fold k l2-norm
      p += __shfl_xor(p, 32);        // combine kg pair within wave
      if (l < 32) ls_pk[pb][w][vp] = p;
      __syncthreads();
      const float kS = ls_pk[pb][0][vp] + ls_pk[pb][1][vp]
                     + ls_pk[pb][2][vp] + ls_pk[pb][3][vp];
      const float dvs = ls_bt[c] * (ls_v[c][vp] - kS) * kn;
      float4 qv[4];
      #pragma unroll
      for (int i = 0; i < 4; ++i) qv[i] = *(const float4*)&ls_q[c][kq * 16 + 4 * i];
      // rank-1 update + readout partial
      float op = 0.f;
      #pragma unroll
      for (int i = 0; i < 4; ++i) {
        S[4*i+0] += kv[i].x * dvs; op += qv[i].x * S[4*i+0];
        S[4*i+1] += kv[i].y * dvs; op += qv[i].y * S[4*i+1];
        S[4*i+2] += kv[i].z * dvs; op += qv[i].z * S[4*i+2];
        S[4*i+3] += kv[i].w * dvs; op += qv[i].w * S[4*i+3];
      }
      op *= ls_qn[c];                // fold q l2-norm * scale
      op += __shfl_xor(op, 32);
      if (l < 32) ls_po[c][w][vp] = op;
      // next step writes ls_pk[pb^1]; its last readers were step c-1,
      // separated by this step's barrier -> safe with 1 barrier/step.
    }
    __syncthreads();
    // ---- cross-wave o reduce + coalesced float4 store ----
    {
      int c = t >> 3, x = (t & 7) * 4;
      float4 a = *(const float4*)&ls_po[c][0][x];
      float4 b = *(const float4*)&ls_po[c][1][x];
      float4 d = *(const float4*)&ls_po[c][2][x];
      float4 e = *(const float4*)&ls_po[c][3][x];
      float4 o;
      o.x = a.x + b.x + d.x + e.x;
      o.y = a.y + b.y + d.y + e.y;
      o.z = a.z + b.z + d.z + e.z;
      o.w = a.w + b.w + d.w + e.w;
      *(float4*)(oh + (size_t)(t0 + c) * V_ + v0 + x) = o;
    }
  }
  // ---- final state ----
  {
    float* sp = out + (size_t)BHn * T_ * V_
                    + ((size_t)bh * K_ + kq * 16) * V_ + v0 + vp;
    #pragma unroll
    for (int i = 0; i < 16; ++i) sp[(size_t)i * V_] = S[i];
  }
}

extern "C" void kernel_launch(void* const* d_in, const int* in_sizes, int n_in,
                              void* d_out, int out_size, void* d_ws, size_t ws_size,
                              hipStream_t stream) {
  const float* q    = (const float*)d_in[0];
  const float* k    = (const float*)d_in[1];
  const float* v    = (const float*)d_in[2];
  const float* g    = (const float*)d_in[3];
  const float* beta = (const float*)d_in[4];
  const float* s0   = (const float*)d_in[5];
  float* out = (float*)d_out;
  hipLaunchKernelGGL(gdn_scan_kernel, dim3(BHn * NS), dim3(256), 0, stream,
                     q, k, v, beta ? g : g, beta, s0, out);
}

// Round 2
// 832.823 us; speedup vs baseline: 1.1042x; 1.1042x over previous
//
#include <hip/hip_runtime.h>
#include <math.h>

namespace {
constexpr int B_ = 4, H_ = 16, T_ = 2048, K_ = 128, V_ = 128;
constexpr int BHn = B_ * H_;
constexpr int CB  = 32;          // time steps staged per chunk
constexpr int NS  = 16;          // V-dim slices (one block each)
constexpr int VS  = V_ / NS;     // 8 columns per block
constexpr int NCH = T_ / CB;     // 64 chunks
constexpr float SCALE = 0.08838834764831845f; // 128^-0.5
}

// x + dpp_permuted(x): quad_perm xor1 = 0xB1, xor2 = 0x4E
template<int CTRL>
__device__ __forceinline__ float dpp_add(float x) {
  int xi = __builtin_bit_cast(int, x);
  int yi = __builtin_amdgcn_update_dpp(0, xi, CTRL, 0xF, 0xF, true);
  return x + __builtin_bit_cast(float, yi);
}
// butterfly sum over lane bits 0,1,2 (the 8 kq groups)
__device__ __forceinline__ float red8(float x) {
  x = dpp_add<0xB1>(x);                       // xor 1
  x = dpp_add<0x4E>(x);                       // xor 2
  int yi = __builtin_amdgcn_ds_swizzle(__builtin_bit_cast(int, x), 0x101F); // xor 4
  return x + __builtin_bit_cast(float, yi);
}

__global__ __launch_bounds__(64, 1)
void gdn_scan_kernel(const float* __restrict__ qg, const float* __restrict__ kgl,
                     const float* __restrict__ vg, const float* __restrict__ gg,
                     const float* __restrict__ bg, const float* __restrict__ s0,
                     float* __restrict__ out)
{
  const int bh = blockIdx.x >> 4;        // head 0..63
  const int v0 = (blockIdx.x & 15) * VS; // V-slice base
  const int t  = threadIdx.x;            // 0..63, single wave
  const int kq = t & 7;                  // k-group (16 rows each)
  const int vp = t >> 3;                 // owned V column 0..7
  const int cl = t & 31;                 // per-lane step index in precompute

  // q/k stored f4-slot-interleaved per row: element e -> slot ((e>>2)&3)*8 + (e>>4)
  // so the step-loop read "slot i*8+kq" hits bank-quad 4*kq: conflict-free.
  __shared__ __align__(16) float ls_q[CB * K_];
  __shared__ __align__(16) float ls_k[CB * K_];
  __shared__ __align__(16) float ls_v[CB][VS];
  __shared__ float ls_g[CB], ls_qa[CB], ls_cbv[CB], ls_cbk[CB];
  __shared__ float ls_dfull;

  // state strip in rescaled coords: Z[i] ~ S[kq*16+i][v0+vp] / D
  float Z[16];
  {
    const float* sp = s0 + ((size_t)bh * K_ + kq * 16) * V_ + v0 + vp;
    #pragma unroll
    for (int i = 0; i < 16; ++i) Z[i] = sp[(size_t)i * V_];
  }

  const float* qh  = qg  + (size_t)bh * T_ * K_;
  const float* kh  = kgl + (size_t)bh * T_ * K_;
  const float* vh  = vg  + (size_t)bh * T_ * V_;
  const float* ghp = gg  + (size_t)bh * T_;
  const float* bhp = bg  + (size_t)bh * T_;
  float* oh = out + (size_t)bh * T_ * V_;

  for (int ch = 0; ch < NCH; ++ch) {
    const int t0 = ch * CB;
    __syncthreads();  // protect LDS reuse vs previous chunk's readers
    // ---- stage q,k (swizzled), v, g ----
    {
      const float4* q4 = (const float4*)(qh + (size_t)t0 * K_);
      const float4* k4 = (const float4*)(kh + (size_t)t0 * K_);
      float4* lq4 = (float4*)ls_q;
      float4* lk4 = (float4*)ls_k;
      #pragma unroll
      for (int r = 0; r < 16; ++r) {
        int F = t + 64 * r;
        int c = F >> 5, m = F & 31;
        int slot = ((m & 3) << 3) | (m >> 2);
        lq4[(c << 5) + slot] = q4[F];
        lk4[(c << 5) + slot] = k4[F];
      }
      ((float4*)&ls_v[t & 31][0])[t >> 5] =
          *(const float4*)(vh + (size_t)(t0 + (t & 31)) * V_ + v0 + ((t >> 5) << 2));
      if (t < CB) ls_g[t] = ghp[t0 + t];
    }
    __syncthreads();
    // ---- per-row l2 norms (rotated, conflict-free) + decay prefix + scalars ----
    {
      const float* rp = (t < 32) ? (ls_q + (t << 7)) : (ls_k + ((t - 32) << 7));
      const float4* rp4 = (const float4*)rp;
      float s = 0.f;
      #pragma unroll
      for (int j = 0; j < 32; ++j) {
        float4 x = rp4[(j + t) & 31];
        s += x.x * x.x + x.y * x.y + x.z * x.z + x.w * x.w;
      }
      float ninv = 1.f / fmaxf(sqrtf(s), 1e-12f);
      float gs = 0.f;
      #pragma unroll
      for (int j = 0; j < 32; ++j) {
        float gj = ls_g[j];
        gs += (j <= cl) ? gj : 0.f;
      }
      float D = expf(gs);   // cumulative decay incl. own step
      if (t < 32) {
        ls_qa[cl] = SCALE * ninv * D;
        if (t == 31) ls_dfull = D;
      } else {
        float bt = bhp[t0 + cl];
        ls_cbv[cl] = bt * ninv / D;     // scales v in du
        ls_cbk[cl] = bt * ninv * ninv;  // scales (k.Z) in du
      }
    }
    __syncthreads();
    // ---- 32 barrier-free recurrence steps ----
    const float4* lq4 = (const float4*)ls_q;
    const float4* lk4 = (const float4*)ls_k;
    #pragma unroll 2
    for (int c = 0; c < CB; ++c) {
      const float4* kr = lk4 + (c << 5) + kq;
      float4 k0 = kr[0], k1 = kr[8], k2 = kr[16], k3 = kr[24];
      float p0 = k0.x * Z[0];  p0 += k0.y * Z[1];  p0 += k0.z * Z[2];  p0 += k0.w * Z[3];
      float p1 = k1.x * Z[4];  p1 += k1.y * Z[5];  p1 += k1.z * Z[6];  p1 += k1.w * Z[7];
      float p2 = k2.x * Z[8];  p2 += k2.y * Z[9];  p2 += k2.z * Z[10]; p2 += k2.w * Z[11];
      float p3 = k3.x * Z[12]; p3 += k3.y * Z[13]; p3 += k3.z * Z[14]; p3 += k3.w * Z[15];
      float s = red8((p0 + p1) + (p2 + p3));      // k . Z  (full K)
      float tv = ls_cbv[c] * ls_v[c][vp];
      float du = tv - ls_cbk[c] * s;              // delta-rule correction, rescaled
      const float4* qr = lq4 + (c << 5) + kq;
      float4 q0 = qr[0], q1 = qr[8], q2 = qr[16], q3 = qr[24];
      float o0, o1, o2, o3;
      Z[0]  += k0.x * du; o0  = q0.x * Z[0];
      Z[1]  += k0.y * du; o0 += q0.y * Z[1];
      Z[2]  += k0.z * du; o0 += q0.z * Z[2];
      Z[3]  += k0.w * du; o0 += q0.w * Z[3];
      Z[4]  += k1.x * du; o1  = q1.x * Z[4];
      Z[5]  += k1.y * du; o1 += q1.y * Z[5];
      Z[6]  += k1.z * du; o1 += q1.z * Z[6];
      Z[7]  += k1.w * du; o1 += q1.w * Z[7];
      Z[8]  += k2.x * du; o2  = q2.x * Z[8];
      Z[9]  += k2.y * du; o2 += q2.y * Z[9];
      Z[10] += k2.z * du; o2 += q2.z * Z[10];
      Z[11] += k2.w * du; o2 += q2.w * Z[11];
      Z[12] += k3.x * du; o3  = q3.x * Z[12];
      Z[13] += k3.y * du; o3 += q3.y * Z[13];
      Z[14] += k3.z * du; o3 += q3.z * Z[14];
      Z[15] += k3.w * du; o3 += q3.w * Z[15];
      float o = red8((o0 + o1) + (o2 + o3)) * ls_qa[c];
      if (kq == 0) oh[(size_t)(t0 + c) * V_ + v0 + vp] = o;
    }
    // ---- un-rescale state back to true coords ----
    float Df = ls_dfull;
    #pragma unroll
    for (int i = 0; i < 16; ++i) Z[i] *= Df;
  }
  // ---- final state ----
  {
    float* sp = out + (size_t)BHn * T_ * V_
                    + ((size_t)bh * K_ + kq * 16) * V_ + v0 + vp;
    #pragma unroll
    for (int i = 0; i < 16; ++i) sp[(size_t)i * V_] = Z[i];
  }
}

extern "C" void kernel_launch(void* const* d_in, const int* in_sizes, int n_in,
                              void* d_out, int out_size, void* d_ws, size_t ws_size,
                              hipStream_t stream) {
  const float* q    = (const float*)d_in[0];
  const float* k    = (const float*)d_in[1];
  const float* v    = (const float*)d_in[2];
  const float* g    = (const float*)d_in[3];
  const float* beta = (const float*)d_in[4];
  const float* s0   = (const float*)d_in[5];
  float* out = (float*)d_out;
  hipLaunchKernelGGL(gdn_scan_kernel, dim3(BHn * NS), dim3(64), 0, stream,
                     q, k, v, g, beta, s0, out);
}

// Round 3
// 389.642 us; speedup vs baseline: 2.3601x; 2.1374x over previous
//
#include <hip/hip_runtime.h>
#include <math.h>

typedef float f32x16 __attribute__((ext_vector_type(16)));
typedef float f32x4v __attribute__((ext_vector_type(4)));
typedef short s16x8 __attribute__((ext_vector_type(8)));

namespace {
constexpr int B_ = 4, H_ = 16, T_ = 2048, K_ = 128, V_ = 128;
constexpr int BHn = B_ * H_;
constexpr int C = 32;            // chunk length
constexpr int NCH = T_ / C;      // 64 chunks
constexpr float SCALE = 0.08838834764831845f; // 128^-0.5
constexpr int SK = 136;          // bf16 row stride for [*][K] arrays (16B-aligned, padded)
constexpr int SR = 40;           // bf16 row stride for [*][C] arrays
constexpr int SF = 36;           // f32 row stride for [C][C] arrays (144B, 16B-aligned)
}

__device__ __forceinline__ ushort f2bf(float x) {
  unsigned u = __builtin_bit_cast(unsigned, x);
  u += 0x7FFF + ((u >> 16) & 1);       // RNE
  return (ushort)(u >> 16);
}

__device__ __forceinline__ f32x16 mm_tile(const ushort* A, const ushort* B,
                                          int lr, int lh) {
  f32x16 acc;
  #pragma unroll
  for (int i = 0; i < 16; ++i) acc[i] = 0.f;
  #pragma unroll
  for (int kb = 0; kb < 8; ++kb) {
    const int off = lr * SK + 16 * kb + 8 * lh;
    s16x8 a = *(const s16x8*)(A + off);
    s16x8 b = *(const s16x8*)(B + off);
    acc = __builtin_amdgcn_mfma_f32_32x32x16_bf16(a, b, acc, 0, 0, 0);
  }
  return acc;
}

__global__ __launch_bounds__(256, 1)
void gdn_chunk_kernel(const float* __restrict__ qg, const float* __restrict__ kg,
                      const float* __restrict__ vg, const float* __restrict__ gg,
                      const float* __restrict__ bg, const float* __restrict__ s0,
                      float* __restrict__ out)
{
  const int bh = blockIdx.x >> 2;        // head 0..63
  const int v0 = (blockIdx.x & 3) * 32;  // V-slice base
  const int t  = threadIdx.x;
  const int w  = t >> 6;                 // wave 0..3
  const int l  = t & 63;
  const int lr = l & 31;
  const int lh = l >> 5;

  __shared__ __align__(16) ushort Kh[C * SK];    // bf16 k-hat [r][k]
  __shared__ __align__(16) ushort Qh[C * SK];    // bf16 scale*q-hat [r][k]
  __shared__ __align__(16) ushort KhT[K_ * SR];  // bf16 k-hat^T [k][r]
  __shared__ __align__(16) ushort SbT[32 * SK];  // bf16 S_in^T [v][k]
  __shared__ __align__(16) ushort UT[32 * SR];   // bf16 U^T [v][r]
  __shared__ __align__(16) float Wm[C * SF], Xm[C * SF], Gm[C * SF], Mm[C * SF];
  __shared__ float Uf[C * 33];                   // f32 u [j][col]
  __shared__ __align__(16) float Vs[C * 32];     // raw v slice [r][v]
  __shared__ float ls_g[C], ls_b[C], ls_eb[C], ls_emb[C];

  // ---- register-resident state: wave w owns k-rows [32w,32w+32), col v0+lr ----
  // reg i -> krow = 32w + (i&3) + 8*(i>>2) + 4*lh  (MFMA 32x32 C/D layout)
  f32x16 S;
  {
    const float* sp = s0 + ((size_t)bh * K_ + 32 * w) * V_ + v0 + lr;
    #pragma unroll
    for (int i = 0; i < 16; ++i) {
      int row = (i & 3) + 8 * (i >> 2) + 4 * lh;
      S[i] = sp[(size_t)row * V_];
      SbT[lr * SK + 32 * w + row] = f2bf(S[i]);
    }
  }

  const float* qh  = qg + (size_t)bh * T_ * K_;
  const float* kh  = kg + (size_t)bh * T_ * K_;
  const float* vh  = vg + (size_t)bh * T_ * V_;
  const float* ghp = gg + (size_t)bh * T_;
  const float* bhp = bg + (size_t)bh * T_;
  float* oh = out + (size_t)bh * T_ * V_;

  for (int ch = 0; ch < NCH; ++ch) {
    const int t0 = ch * C;
    __syncthreads();   // prev ph4 readers done (also covers initial SbT/S)

    // ================= ph1: stage & normalize =================
    {
      const int r = t >> 3, c8 = t & 7;
      const float4* q4 = (const float4*)(qh + (size_t)(t0 + r) * K_);
      const float4* k4 = (const float4*)(kh + (size_t)(t0 + r) * K_);
      float4 qv[4], kv[4];
      float sq = 0.f, sk = 0.f;
      #pragma unroll
      for (int c = 0; c < 4; ++c) {
        qv[c] = q4[c8 + 8 * c];
        kv[c] = k4[c8 + 8 * c];
        sq += qv[c].x * qv[c].x + qv[c].y * qv[c].y + qv[c].z * qv[c].z + qv[c].w * qv[c].w;
        sk += kv[c].x * kv[c].x + kv[c].y * kv[c].y + kv[c].z * kv[c].z + kv[c].w * kv[c].w;
      }
      sq += __shfl_xor(sq, 1); sq += __shfl_xor(sq, 2); sq += __shfl_xor(sq, 4);
      sk += __shfl_xor(sk, 1); sk += __shfl_xor(sk, 2); sk += __shfl_xor(sk, 4);
      const float niq = SCALE / fmaxf(sqrtf(sq), 1e-12f);
      const float nik = 1.0f / fmaxf(sqrtf(sk), 1e-12f);
      #pragma unroll
      for (int c = 0; c < 4; ++c) {
        const int f4 = c8 + 8 * c;
        ushort pk0 = f2bf(kv[c].x * nik), pk1 = f2bf(kv[c].y * nik);
        ushort pk2 = f2bf(kv[c].z * nik), pk3 = f2bf(kv[c].w * nik);
        ushort pq0 = f2bf(qv[c].x * niq), pq1 = f2bf(qv[c].y * niq);
        ushort pq2 = f2bf(qv[c].z * niq), pq3 = f2bf(qv[c].w * niq);
        uint2 upk, upq;
        upk.x = (unsigned)pk0 | ((unsigned)pk1 << 16);
        upk.y = (unsigned)pk2 | ((unsigned)pk3 << 16);
        upq.x = (unsigned)pq0 | ((unsigned)pq1 << 16);
        upq.y = (unsigned)pq2 | ((unsigned)pq3 << 16);
        *(uint2*)(Kh + r * SK + f4 * 4) = upk;
        *(uint2*)(Qh + r * SK + f4 * 4) = upq;
        KhT[(f4 * 4 + 0) * SR + r] = pk0;
        KhT[(f4 * 4 + 1) * SR + r] = pk1;
        KhT[(f4 * 4 + 2) * SR + r] = pk2;
        KhT[(f4 * 4 + 3) * SR + r] = pk3;
      }
      float4 vv = ((const float4*)(vh + (size_t)(t0 + r) * V_ + v0))[c8];
      *(float4*)(Vs + r * 32 + c8 * 4) = vv;
      if (t < C)               ls_g[t]      = ghp[t0 + t];
      else if (t < 2 * C)      ls_b[t - C]  = bhp[t0 + t - C];
    }
    __syncthreads();

    // ================= ph2: MFMA W/X/G/M + decay prefix =================
    if (w == 3 && l < 32) {   // inclusive prefix of g -> e^{b}, e^{-b}
      float x = ls_g[l];
      #pragma unroll
      for (int d = 1; d < 32; d <<= 1) {
        float y = __shfl_up(x, d);
        if (l >= d) x += y;
      }
      ls_eb[l]  = expf(x);
      ls_emb[l] = expf(-x);
    }
    {
      f32x16 acc;
      float* dst;
      if (w == 0)      { acc = mm_tile(Kh, SbT, lr, lh); dst = Wm; }
      else if (w == 1) { acc = mm_tile(Qh, SbT, lr, lh); dst = Xm; }
      else if (w == 2) { acc = mm_tile(Qh, Kh,  lr, lh); dst = Gm; }
      else             { acc = mm_tile(Kh, Kh,  lr, lh); dst = Mm; }
      #pragma unroll
      for (int i = 0; i < 16; ++i) {
        int row = (i & 3) + 8 * (i >> 2) + 4 * lh;
        float val = acc[i];
        if (w == 2 && lr > row) val = 0.f;   // mask G to j<=r
        dst[row * SF + lr] = val;
      }
    }
    __syncthreads();

    // ================= ph3: triangular solve (wave 0) =================
    if (w == 0) {
      const int col = lr;
      float u[32];
      #pragma unroll
      for (int r = 0; r < 32; ++r) {
        float a = ls_emb[r] * Vs[r * 32 + col] - Wm[r * SF + col];
        const float* mr = Mm + r * SF;
        #pragma unroll
        for (int jb = 0; jb < (r & ~3); jb += 4) {
          float4 m4 = *(const float4*)(mr + jb);
          a = fmaf(-m4.x, u[jb + 0], a);
          a = fmaf(-m4.y, u[jb + 1], a);
          a = fmaf(-m4.z, u[jb + 2], a);
          a = fmaf(-m4.w, u[jb + 3], a);
        }
        #pragma unroll
        for (int j = (r & ~3); j < r; ++j) a = fmaf(-mr[j], u[j], a);
        u[r] = ls_b[r] * a;
      }
      if (l < 32) {
        #pragma unroll
        for (int j = 0; j < 32; ++j) Uf[j * 33 + col] = u[j];
        #pragma unroll
        for (int jb = 0; jb < 4; ++jb) {
          s16x8 pk;
          #pragma unroll
          for (int e = 0; e < 8; ++e) pk[e] = (short)f2bf(u[8 * jb + e]);
          *(s16x8*)(UT + col * SR + 8 * jb) = pk;
        }
      }
    }
    __syncthreads();

    // ================= ph4: state update (MFMA) + output =================
    {
      // S <- e^{b31} (S + Khat^T U) for this wave's k-quadrant
      f32x16 acc = S;
      #pragma unroll
      for (int rb = 0; rb < 2; ++rb) {
        s16x8 a = *(const s16x8*)(KhT + (32 * w + lr) * SR + 16 * rb + 8 * lh);
        s16x8 b = *(const s16x8*)(UT + lr * SR + 16 * rb + 8 * lh);
        acc = __builtin_amdgcn_mfma_f32_32x32x16_bf16(a, b, acc, 0, 0, 0);
      }
      // O rows 8w..8w+7 : o_r = e^{b_r} (X[r] + sum_j G[r][j] u_j)
      float uv[32];
      #pragma unroll
      for (int j = 0; j < 32; ++j) uv[j] = Uf[j * 33 + lr];
      #pragma unroll
      for (int m = 0; m < 4; ++m) {
        const int r = 8 * w + 4 * lh + m;
        float o = Xm[r * SF + lr];
        const float* gr = Gm + r * SF;
        #pragma unroll
        for (int jb = 0; jb < 32; jb += 4) {
          float4 g4 = *(const float4*)(gr + jb);
          o = fmaf(g4.x, uv[jb + 0], o);
          o = fmaf(g4.y, uv[jb + 1], o);
          o = fmaf(g4.z, uv[jb + 2], o);
          o = fmaf(g4.w, uv[jb + 3], o);
        }
        oh[(size_t)(t0 + r) * V_ + v0 + lr] = ls_eb[r] * o;
      }
      const float ebL = ls_eb[31];
      #pragma unroll
      for (int i = 0; i < 16; ++i) {
        S[i] = ebL * acc[i];
        int row = (i & 3) + 8 * (i >> 2) + 4 * lh;
        SbT[lr * SK + 32 * w + row] = f2bf(S[i]);
      }
    }
  }

  // ---- final state ----
  {
    float* sp = out + (size_t)BHn * T_ * V_
                    + ((size_t)bh * K_ + 32 * w) * V_ + v0 + lr;
    #pragma unroll
    for (int i = 0; i < 16; ++i) {
      int row = (i & 3) + 8 * (i >> 2) + 4 * lh;
      sp[(size_t)row * V_] = S[i];
    }
  }
}

extern "C" void kernel_launch(void* const* d_in, const int* in_sizes, int n_in,
                              void* d_out, int out_size, void* d_ws, size_t ws_size,
                              hipStream_t stream) {
  const float* q    = (const float*)d_in[0];
  const float* k    = (const float*)d_in[1];
  const float* v    = (const float*)d_in[2];
  const float* g    = (const float*)d_in[3];
  const float* beta = (const float*)d_in[4];
  const float* s0   = (const float*)d_in[5];
  float* out = (float*)d_out;
  hipLaunchKernelGGL(gdn_chunk_kernel, dim3(BHn * 4), dim3(256), 0, stream,
                     q, k, v, g, beta, s0, out);
}

// Round 4
// 354.956 us; speedup vs baseline: 2.5907x; 1.0977x over previous
//
#include <hip/hip_runtime.h>
#include <math.h>

typedef float f32x16 __attribute__((ext_vector_type(16)));
typedef short s16x8 __attribute__((ext_vector_type(8)));

namespace {
constexpr int B_ = 4, H_ = 16, T_ = 2048, K_ = 128, V_ = 128;
constexpr int BHn = B_ * H_;
constexpr int C = 32;            // chunk length
constexpr int NCH = T_ / C;      // 64 chunks
constexpr float SCALE = 0.08838834764831845f; // 128^-0.5
constexpr int SK = 136;          // bf16 row stride for [*][K] arrays
constexpr int SR = 40;           // bf16 row stride for [*][C] arrays
constexpr int SF = 36;           // f32 row stride for [C][C] arrays
}

__device__ __forceinline__ ushort f2bf(float x) {
  unsigned u = __builtin_bit_cast(unsigned, x);
  u += 0x7FFF + ((u >> 16) & 1);       // RNE
  return (ushort)(u >> 16);
}

// barrier that waits only on LDS ops: prefetch global loads / O-stores stay in flight
__device__ __forceinline__ void bar_lds() {
  asm volatile("s_waitcnt lgkmcnt(0)" ::: "memory");
  __builtin_amdgcn_s_barrier();
  asm volatile("" ::: "memory");
}

__device__ __forceinline__ f32x16 mm_tile(const ushort* A, const ushort* B,
                                          int lr, int lh) {
  f32x16 a0, a1;
  #pragma unroll
  for (int i = 0; i < 16; ++i) { a0[i] = 0.f; a1[i] = 0.f; }
  #pragma unroll
  for (int kb = 0; kb < 8; kb += 2) {
    const int o0 = lr * SK + 16 * kb + 8 * lh, o1 = o0 + 16;
    a0 = __builtin_amdgcn_mfma_f32_32x32x16_bf16(*(const s16x8*)(A + o0),
                                                 *(const s16x8*)(B + o0), a0, 0, 0, 0);
    a1 = __builtin_amdgcn_mfma_f32_32x32x16_bf16(*(const s16x8*)(A + o1),
                                                 *(const s16x8*)(B + o1), a1, 0, 0, 0);
  }
  return a0 + a1;
}

__global__ __launch_bounds__(256, 1)
void gdn_chunk_kernel(const float* __restrict__ qg, const float* __restrict__ kg,
                      const float* __restrict__ vg, const float* __restrict__ gg,
                      const float* __restrict__ bg, const float* __restrict__ s0,
                      float* __restrict__ out)
{
  const int bh = blockIdx.x >> 2;        // head 0..63
  const int v0 = (blockIdx.x & 3) * 32;  // V-slice base
  const int t  = threadIdx.x;
  const int w  = t >> 6;                 // wave 0..3
  const int l  = t & 63;
  const int lr = l & 31;
  const int lh = l >> 5;
  const int r8 = t >> 3;                 // staging row 0..31
  const int c8 = t & 7;                  // staging float4 slot 0..7

  __shared__ __align__(16) ushort Kh[C * SK];    // bf16 k-hat [r][k]
  __shared__ __align__(16) ushort Qh[C * SK];    // bf16 scale*q-hat [r][k]
  __shared__ __align__(16) ushort KhT[K_ * SR];  // bf16 k-hat^T [k][r]
  __shared__ __align__(16) ushort SbT[32 * SK];  // bf16 S^T [v][k]
  __shared__ __align__(16) ushort UT[32 * SR];   // bf16 U^T [v][r]
  __shared__ __align__(16) float Wm[C * SF], Xm[C * SF], Gm[C * SF], Mm[C * SF];
  __shared__ __align__(16) float Vs[C * 32];     // raw v slice [r][v]
  __shared__ float ls_g[C], ls_b[C], ls_eb[C], ls_emb[C];

  // ---- register-resident state: wave w owns k-rows [32w,32w+32), col v0+lr ----
  f32x16 S;
  {
    const float* sp = s0 + ((size_t)bh * K_ + 32 * w) * V_ + v0 + lr;
    #pragma unroll
    for (int i = 0; i < 16; i += 2) {
      int row = (i & 3) + 8 * (i >> 2) + 4 * lh;
      S[i]     = sp[(size_t)row * V_];
      S[i + 1] = sp[(size_t)(row + 1) * V_];
      unsigned pack = (unsigned)f2bf(S[i]) | ((unsigned)f2bf(S[i + 1]) << 16);
      *(unsigned*)(SbT + lr * SK + 32 * w + row) = pack;
    }
  }

  const float* qh  = qg + (size_t)bh * T_ * K_;
  const float* kh  = kg + (size_t)bh * T_ * K_;
  const float* vh  = vg + (size_t)bh * T_ * V_;
  const float* ghp = gg + (size_t)bh * T_;
  const float* bhp = bg + (size_t)bh * T_;
  float* oh = out + (size_t)bh * T_ * V_;

  // ---- prologue: prefetch chunk 0 into registers ----
  float4 pq[4], pk[4], pv;
  float pg = 0.f;
  {
    const float4* q4 = (const float4*)(qh + (size_t)r8 * K_);
    const float4* k4 = (const float4*)(kh + (size_t)r8 * K_);
    #pragma unroll
    for (int c = 0; c < 4; ++c) { pq[c] = q4[c8 + 8 * c]; pk[c] = k4[c8 + 8 * c]; }
    pv = ((const float4*)(vh + (size_t)r8 * V_ + v0))[c8];
    if (t < C)          pg = ghp[t];
    else if (t < 2 * C) pg = bhp[t - C];
  }

  for (int ch = 0; ch < NCH; ++ch) {
    const int t0 = ch * C;
    bar_lds();   // prev chunk's ph4 LDS reads done before we overwrite staging

    // ================= ph1: normalize + store staged regs =================
    {
      float sq = 0.f, sk = 0.f;
      #pragma unroll
      for (int c = 0; c < 4; ++c) {
        sq += pq[c].x * pq[c].x + pq[c].y * pq[c].y + pq[c].z * pq[c].z + pq[c].w * pq[c].w;
        sk += pk[c].x * pk[c].x + pk[c].y * pk[c].y + pk[c].z * pk[c].z + pk[c].w * pk[c].w;
      }
      sq += __shfl_xor(sq, 1); sq += __shfl_xor(sq, 2); sq += __shfl_xor(sq, 4);
      sk += __shfl_xor(sk, 1); sk += __shfl_xor(sk, 2); sk += __shfl_xor(sk, 4);
      const float niq = SCALE / fmaxf(sqrtf(sq), 1e-12f);
      const float nik = 1.0f / fmaxf(sqrtf(sk), 1e-12f);
      #pragma unroll
      for (int c = 0; c < 4; ++c) {
        const int f4 = c8 + 8 * c;
        ushort k0 = f2bf(pk[c].x * nik), k1 = f2bf(pk[c].y * nik);
        ushort k2 = f2bf(pk[c].z * nik), k3 = f2bf(pk[c].w * nik);
        ushort q0 = f2bf(pq[c].x * niq), q1 = f2bf(pq[c].y * niq);
        ushort q2 = f2bf(pq[c].z * niq), q3 = f2bf(pq[c].w * niq);
        uint2 upk, upq;
        upk.x = (unsigned)k0 | ((unsigned)k1 << 16);
        upk.y = (unsigned)k2 | ((unsigned)k3 << 16);
        upq.x = (unsigned)q0 | ((unsigned)q1 << 16);
        upq.y = (unsigned)q2 | ((unsigned)q3 << 16);
        *(uint2*)(Kh + r8 * SK + f4 * 4) = upk;
        *(uint2*)(Qh + r8 * SK + f4 * 4) = upq;
        KhT[(f4 * 4 + 0) * SR + r8] = k0;
        KhT[(f4 * 4 + 1) * SR + r8] = k1;
        KhT[(f4 * 4 + 2) * SR + r8] = k2;
        KhT[(f4 * 4 + 3) * SR + r8] = k3;
      }
      *(float4*)(Vs + r8 * 32 + c8 * 4) = pv;
      if (t < C)          ls_g[t]     = pg;
      else if (t < 2 * C) ls_b[t - C] = pg;
    }
    // ---- prefetch next chunk (stays in flight across lgkm-only barriers) ----
    if (ch + 1 < NCH) {
      const int t1 = t0 + C;
      const float4* q4 = (const float4*)(qh + (size_t)(t1 + r8) * K_);
      const float4* k4 = (const float4*)(kh + (size_t)(t1 + r8) * K_);
      #pragma unroll
      for (int c = 0; c < 4; ++c) { pq[c] = q4[c8 + 8 * c]; pk[c] = k4[c8 + 8 * c]; }
      pv = ((const float4*)(vh + (size_t)(t1 + r8) * V_ + v0))[c8];
      if (t < C)          pg = ghp[t1 + t];
      else if (t < 2 * C) pg = bhp[t1 + t - C];
    }
    bar_lds();

    // ================= ph2: MFMA W/X/G/M + decay prefix =================
    if (w == 3 && l < 32) {   // inclusive prefix of g -> e^{b}, e^{-b}
      float x = ls_g[l];
      #pragma unroll
      for (int d = 1; d < 32; d <<= 1) {
        float y = __shfl_up(x, d);
        if (l >= d) x += y;
      }
      ls_eb[l]  = expf(x);
      ls_emb[l] = expf(-x);
    }
    {
      f32x16 acc;
      float* dst;
      if (w == 0)      { acc = mm_tile(Kh, SbT, lr, lh); dst = Wm; }
      else if (w == 1) { acc = mm_tile(Qh, SbT, lr, lh); dst = Xm; }
      else if (w == 2) { acc = mm_tile(Qh, Kh,  lr, lh); dst = Gm; }
      else             { acc = mm_tile(Kh, Kh,  lr, lh); dst = Mm; }
      #pragma unroll
      for (int i = 0; i < 16; ++i) {
        int row = (i & 3) + 8 * (i >> 2) + 4 * lh;
        float val = acc[i];
        if (w == 2 && lr > row) val = 0.f;   // mask G to j<=r
        dst[row * SF + lr] = val;
      }
    }
    bar_lds();

    // ================= ph3: redundant per-wave solve (u in registers) =====
    float u[32];
    {
      const int col = lr;
      #pragma unroll
      for (int r = 0; r < 32; ++r) {
        float a = ls_emb[r] * Vs[r * 32 + col] - Wm[r * SF + col];
        float p0 = 0.f, p1 = 0.f, p2 = 0.f, p3 = 0.f;
        const float* mr = Mm + r * SF;
        #pragma unroll
        for (int jb = 0; jb + 4 <= r; jb += 4) {
          float4 m4 = *(const float4*)(mr + jb);
          p0 = fmaf(m4.x, u[jb + 0], p0);
          p1 = fmaf(m4.y, u[jb + 1], p1);
          p2 = fmaf(m4.z, u[jb + 2], p2);
          p3 = fmaf(m4.w, u[jb + 3], p3);
        }
        #pragma unroll
        for (int j = (r & ~3); j < r; ++j) p1 = fmaf(mr[j], u[j], p1);
        a -= (p0 + p1) + (p2 + p3);
        u[r] = ls_b[r] * a;
      }
    }
    if (w == 0 && l < 32) {   // one copy of bf16 U^T for the state MFMA
      #pragma unroll
      for (int jb = 0; jb < 4; ++jb) {
        s16x8 pkv;
        #pragma unroll
        for (int e = 0; e < 8; ++e) pkv[e] = (short)f2bf(u[8 * jb + e]);
        *(s16x8*)(UT + lr * SR + 8 * jb) = pkv;
      }
    }
    // ---- O rows from register u: o_r = e^{b_r}(X[r] + sum_j G[r][j] u_j) ----
    {
      #pragma unroll
      for (int m = 0; m < 4; ++m) {
        const int r = 8 * w + 4 * lh + m;
        float o0 = Xm[r * SF + lr], o1 = 0.f, o2 = 0.f, o3 = 0.f;
        const float* gr = Gm + r * SF;
        #pragma unroll
        for (int jb = 0; jb < 32; jb += 4) {
          float4 g4 = *(const float4*)(gr + jb);
          o0 = fmaf(g4.x, u[jb + 0], o0);
          o1 = fmaf(g4.y, u[jb + 1], o1);
          o2 = fmaf(g4.z, u[jb + 2], o2);
          o3 = fmaf(g4.w, u[jb + 3], o3);
        }
        oh[(size_t)(t0 + r) * V_ + v0 + lr] = ls_eb[r] * ((o0 + o1) + (o2 + o3));
      }
    }
    bar_lds();   // UT visible

    // ================= ph4: state update (MFMA) =================
    {
      f32x16 acc = S;
      #pragma unroll
      for (int rb = 0; rb < 2; ++rb) {
        s16x8 a = *(const s16x8*)(KhT + (32 * w + lr) * SR + 16 * rb + 8 * lh);
        s16x8 b = *(const s16x8*)(UT + lr * SR + 16 * rb + 8 * lh);
        acc = __builtin_amdgcn_mfma_f32_32x32x16_bf16(a, b, acc, 0, 0, 0);
      }
      const float ebL = ls_eb[31];
      #pragma unroll
      for (int i = 0; i < 16; i += 2) {
        S[i]     = ebL * acc[i];
        S[i + 1] = ebL * acc[i + 1];
        int row = (i & 3) + 8 * (i >> 2) + 4 * lh;
        unsigned pack = (unsigned)f2bf(S[i]) | ((unsigned)f2bf(S[i + 1]) << 16);
        *(unsigned*)(SbT + lr * SK + 32 * w + row) = pack;
      }
    }
  }

  // ---- final state ----
  {
    float* sp = out + (size_t)BHn * T_ * V_
                    + ((size_t)bh * K_ + 32 * w) * V_ + v0 + lr;
    #pragma unroll
    for (int i = 0; i < 16; ++i) {
      int row = (i & 3) + 8 * (i >> 2) + 4 * lh;
      sp[(size_t)row * V_] = S[i];
    }
  }
}

extern "C" void kernel_launch(void* const* d_in, const int* in_sizes, int n_in,
                              void* d_out, int out_size, void* d_ws, size_t ws_size,
                              hipStream_t stream) {
  const float* q    = (const float*)d_in[0];
  const float* k    = (const float*)d_in[1];
  const float* v    = (const float*)d_in[2];
  const float* g    = (const float*)d_in[3];
  const float* beta = (const float*)d_in[4];
  const float* s0   = (const float*)d_in[5];
  float* out = (float*)d_out;
  hipLaunchKernelGGL(gdn_chunk_kernel, dim3(BHn * 4), dim3(256), 0, stream,
                     q, k, v, g, beta, s0, out);
}